// Round 1
// baseline (398.879 us; speedup 1.0000x reference)
//
#include <hip/hip_runtime.h>

// ---------------------------------------------------------------------------
// TurboQuantAttention: PolarQuant/QJL compress-decompress + attention.
// Strategy: rotate q/k/v by R (fp32, bin-exact vs reference), global absmax,
// quantize+dequant k,v in ROTATED space (orthogonal R lets us skip inverse
// rotations inside attention), bf16-MFMA flash attention with a static
// per-row softmax bound (no online max), final @ R^T in fp32.
// ---------------------------------------------------------------------------

typedef float  f32x4  __attribute__((ext_vector_type(4)));
typedef __bf16 bf16x8 __attribute__((ext_vector_type(8)));
typedef __bf16 bf16x4 __attribute__((ext_vector_type(4)));

#define SLEN  2048
#define DH    128
#define NROWS 65536   // B*H*S = 2*16*2048

static __device__ __forceinline__ f32x4 mfma16(bf16x8 a, bf16x8 b, f32x4 c) {
  return __builtin_amdgcn_mfma_f32_16x16x32_bf16(a, b, c, 0, 0, 0);
}

// quantize->dequantize one element, op-order identical to reference (fp32)
static __device__ __forceinline__ float qdq(float xr, float xmax, float qs) {
  float xs = xr / xmax * 3.5f;
  float xq = rintf(xs * 4.0f) * 0.25f;          // jnp.round = RNE = rintf
  xq = fminf(3.5f, fmaxf(-3.5f, xq));
  float res = xs - xq;
  float sg = (res > 0.0f) ? 1.0f : ((res < 0.0f) ? -1.0f : 0.0f);
  float xc = xq + sg * qs * xmax;
  return xc / 3.5f * xmax;
}

static __device__ __forceinline__ unsigned short bfbits(float f) {
  __bf16 b = (__bf16)f;
  return __builtin_bit_cast(unsigned short, b);
}

// ---------------------------------------------------------------------------
// rotate_kernel: OUT[row][:] = X[row][:] @ R   (MODE 0,1,2)
//                OUT[row][:] = X[row][:] @ R^T (MODE 3)
// MODE 0: q -> bf16 out scaled by 1/sqrt(D), also row norms -> qn
// MODE 1/2: k/v -> fp32 out + per-block absmax -> part
// MODE 3: unrotate, fp32 out
// 64 rows/block, 256 threads; thread computes 4 rows x 8 cols
// (cols dg*4..+3 and 64+dg*4..+3 to spread LDS banks).
// ---------------------------------------------------------------------------
template<int MODE>
__global__ __launch_bounds__(256) void rotate_kernel(
    const float* __restrict__ X, const float* __restrict__ R,
    void* __restrict__ OUTv, float* __restrict__ part, float* __restrict__ qn)
{
  __shared__ float Rs[32][128];   // [contract e][out d]
  __shared__ float Xt[32][68];    // [contract e][row], padded
  __shared__ float Red[64];

  const int tid = threadIdx.x;
  const long r0 = (long)blockIdx.x * 64;
  const int rg = tid >> 4;        // 0..15 -> rows rg*4..+3
  const int dg = tid & 15;        // cols dg*4..+3 and 64+dg*4..+3

  f32x4 accA[4], accB[4];
  #pragma unroll
  for (int r = 0; r < 4; ++r) {
    accA[r] = (f32x4){0.f,0.f,0.f,0.f};
    accB[r] = (f32x4){0.f,0.f,0.f,0.f};
  }

  for (int ec = 0; ec < 128; ec += 32) {
    __syncthreads();
    if (MODE != 3) {
      // Rs[e][d] = R[ec+e][d]
      int e = tid >> 3, c = tid & 7;
      const f32x4* src = (const f32x4*)&R[(ec + e) * 128 + c * 16];
      f32x4* dst = (f32x4*)&Rs[e][c * 16];
      dst[0] = src[0]; dst[1] = src[1]; dst[2] = src[2]; dst[3] = src[3];
    } else {
      // Rs[e][d] = R[d][ec+e]  (transposed stage)
      int d = tid >> 1, h = tid & 1;
      const float* src = &R[d * 128 + ec + h * 16];
      #pragma unroll
      for (int j = 0; j < 16; ++j) Rs[h * 16 + j][d] = src[j];
    }
    {
      // Xt[e][row] = X[r0+row][ec+e]
      int row = tid & 63;
      int eo = (tid >> 6) * 8;
      const float* src = &X[(r0 + row) * 128 + ec + eo];
      #pragma unroll
      for (int j = 0; j < 8; ++j) Xt[eo + j][row] = src[j];
    }
    __syncthreads();
    #pragma unroll 4
    for (int e = 0; e < 32; ++e) {
      f32x4 xv = *(const f32x4*)&Xt[e][rg * 4];
      f32x4 ra = *(const f32x4*)&Rs[e][dg * 4];
      f32x4 rb = *(const f32x4*)&Rs[e][64 + dg * 4];
      #pragma unroll
      for (int r = 0; r < 4; ++r) {
        accA[r] += xv[r] * ra;
        accB[r] += xv[r] * rb;
      }
    }
  }

  if constexpr (MODE == 0) {
    __bf16* OUT = (__bf16*)OUTv;
    const float sc = 0.08838834764831843f;   // 1/sqrt(128)
    float ss[4];
    #pragma unroll
    for (int r = 0; r < 4; ++r) {
      f32x4 a = accA[r] * sc, b = accB[r] * sc;
      bf16x4 lo, hi;
      #pragma unroll
      for (int j = 0; j < 4; ++j) { lo[j] = (__bf16)a[j]; hi[j] = (__bf16)b[j]; }
      long row = r0 + rg * 4 + r;
      *(bf16x4*)&OUT[row * 128 + dg * 4] = lo;
      *(bf16x4*)&OUT[row * 128 + 64 + dg * 4] = hi;
      ss[r] = a[0]*a[0] + a[1]*a[1] + a[2]*a[2] + a[3]*a[3]
            + b[0]*b[0] + b[1]*b[1] + b[2]*b[2] + b[3]*b[3];
    }
    if (tid < 64) Red[tid] = 0.f;
    __syncthreads();
    #pragma unroll
    for (int r = 0; r < 4; ++r) atomicAdd(&Red[rg * 4 + r], ss[r]);
    __syncthreads();
    if (tid < 64) qn[r0 + tid] = sqrtf(Red[tid]);
  } else if constexpr (MODE == 1 || MODE == 2) {
    float* OUT = (float*)OUTv;
    float tm = 0.f;
    #pragma unroll
    for (int r = 0; r < 4; ++r) {
      long row = r0 + rg * 4 + r;
      *(f32x4*)&OUT[row * 128 + dg * 4] = accA[r];
      *(f32x4*)&OUT[row * 128 + 64 + dg * 4] = accB[r];
      #pragma unroll
      for (int j = 0; j < 4; ++j)
        tm = fmaxf(tm, fmaxf(fabsf(accA[r][j]), fabsf(accB[r][j])));
    }
    #pragma unroll
    for (int m = 1; m <= 32; m <<= 1) tm = fmaxf(tm, __shfl_xor(tm, m, 64));
    if ((tid & 63) == 0) Red[tid >> 6] = tm;
    __syncthreads();
    if (tid == 0) part[blockIdx.x] = fmaxf(fmaxf(Red[0], Red[1]), fmaxf(Red[2], Red[3]));
  } else {
    float* OUT = (float*)OUTv;
    #pragma unroll
    for (int r = 0; r < 4; ++r) {
      long row = r0 + rg * 4 + r;
      *(f32x4*)&OUT[row * 128 + dg * 4] = accA[r];
      *(f32x4*)&OUT[row * 128 + 64 + dg * 4] = accB[r];
    }
  }
}

// reduce 1024 k-partials and 1024 v-partials to kvmax[0], kvmax[1]
__global__ __launch_bounds__(256) void reduce_max_kernel(
    const float* __restrict__ part, float* __restrict__ outmax)
{
  __shared__ float s4[4];
  const int tid = threadIdx.x;
  for (int which = 0; which < 2; ++which) {
    const float* p = part + which * 1024;
    float m = fmaxf(fmaxf(p[tid], p[tid + 256]), fmaxf(p[tid + 512], p[tid + 768]));
    #pragma unroll
    for (int msk = 1; msk <= 32; msk <<= 1) m = fmaxf(m, __shfl_xor(m, msk, 64));
    if ((tid & 63) == 0) s4[tid >> 6] = m;
    __syncthreads();
    if (tid == 0) outmax[which] = fmaxf(fmaxf(s4[0], s4[1]), fmaxf(s4[2], s4[3]));
    __syncthreads();
  }
}

// elementwise quantize+dequant k -> bf16 natural layout
__global__ __launch_bounds__(256) void quantize_k_kernel(
    const float* __restrict__ xr, const float* __restrict__ gmax,
    const float* __restrict__ qjl, __bf16* __restrict__ out)
{
  const float xmax = gmax[0] + 1e-8f;
  const float qs = qjl[0];
  long i = ((long)blockIdx.x * 256 + threadIdx.x) * 4;
  f32x4 x = *(const f32x4*)&xr[i];
  bf16x4 ov;
  #pragma unroll
  for (int j = 0; j < 4; ++j) ov[j] = (__bf16)qdq(x[j], xmax, qs);
  *(bf16x4*)&out[i] = ov;
}

// quantize+dequant v -> bf16 TRANSPOSED per head: vdt[bh][d][s]
// one block per 32-row tile; transpose via LDS (2 keys packed per dword)
__global__ __launch_bounds__(256) void quantize_vt_kernel(
    const float* __restrict__ vr, const float* __restrict__ gmax,
    const float* __restrict__ qjl, __bf16* __restrict__ vdt)
{
  __shared__ unsigned int Ts32[128][18];   // [d][key pair], 36 bf16/row
  const int tid = threadIdx.x;
  const int bh = blockIdx.x >> 6;
  const int s0 = (blockIdx.x & 63) * 32;
  const float xmax = gmax[0] + 1e-8f;
  const float qs = qjl[0];

  const int sp  = tid & 15;   // key pair: rows sp*2, sp*2+1
  const int dch = tid >> 4;   // 8 d's: dch*8..+7
  const long rb = (long)bh * SLEN + s0;
  const float* p0 = &vr[(rb + sp * 2    ) * 128 + dch * 8];
  const float* p1 = &vr[(rb + sp * 2 + 1) * 128 + dch * 8];
  #pragma unroll
  for (int j = 0; j < 8; ++j) {
    unsigned a = bfbits(qdq(p0[j], xmax, qs));
    unsigned b = bfbits(qdq(p1[j], xmax, qs));
    Ts32[dch * 8 + j][sp] = a | (b << 16);
  }
  __syncthreads();
  const int d = tid >> 1, h = tid & 1;
  const unsigned long long* srcq =
      (const unsigned long long*)((const unsigned short*)&Ts32[d][0] + h * 16);
  unsigned long long* dstq =
      (unsigned long long*)&vdt[((long)bh * DH + d) * SLEN + s0 + h * 16];
  dstq[0] = srcq[0]; dstq[1] = srcq[1]; dstq[2] = srcq[2]; dstq[3] = srcq[3];
}

// ---------------------------------------------------------------------------
// Flash attention in rotated space, bf16 MFMA 16x16x32.
// 4 waves/block, 32 q-rows/wave (2 groups of 16), 32-key tiles.
// Static per-row softmax bound M = 0.5 * qn * sqrt(D)*max|kd| (no online max).
// ---------------------------------------------------------------------------
__global__ __launch_bounds__(256, 2) void attn_kernel(
    const __bf16* __restrict__ qb, const __bf16* __restrict__ kd,
    const __bf16* __restrict__ vdt, const float* __restrict__ qn,
    const float* __restrict__ kvmax, const float* __restrict__ qjl,
    float* __restrict__ orot)
{
  __shared__ __bf16 Ks[32][DH];      // K tile, natural [key][d]
  __shared__ __bf16 Vt[DH][40];      // V tile, [d][key], padded
  __shared__ float  Ps[4][32][36];   // per-wave P, [q][key], padded

  const int tid  = threadIdx.x;
  const int wave = tid >> 6;
  const int lane = tid & 63;
  const int L    = lane & 15;
  const int quad = lane >> 4;
  const int head = blockIdx.x & 31;          // XCD-friendly: head = bid%32
  const int qt   = blockIdx.x >> 5;
  const int qbase = qt * 128 + wave * 32;
  const long hrow = (long)head * SLEN;

  const float xmax = kvmax[0] + 1e-8f;
  // 0.5 * CauchySchwarz bound (1.02 covers bf16 rounding); overflow-safe both ways
  const float Bk = 11.313708499f * ((3.5f + qjl[0] * xmax) * xmax / 3.5f) * 1.02f * 0.5f;

  // Q fragments (A-layout: m=lane&15, k=quad*8+j), scale already folded in qb
  bf16x8 aq[2][4];
  #pragma unroll
  for (int g = 0; g < 2; ++g)
    #pragma unroll
    for (int c = 0; c < 4; ++c)
      aq[g][c] = *(const bf16x8*)&qb[(hrow + qbase + g * 16 + L) * DH + c * 32 + quad * 8];

  float Mrow[2][4], lrow[2][4];
  #pragma unroll
  for (int g = 0; g < 2; ++g)
    #pragma unroll
    for (int r = 0; r < 4; ++r) {
      Mrow[g][r] = qn[hrow + qbase + g * 16 + quad * 4 + r] * Bk;
      lrow[g][r] = 0.f;
    }

  f32x4 o[2][8];
  #pragma unroll
  for (int g = 0; g < 2; ++g)
    #pragma unroll
    for (int c = 0; c < 8; ++c) o[g][c] = (f32x4){0.f,0.f,0.f,0.f};

  for (int kt = 0; kt < SLEN / 32; ++kt) {
    __syncthreads();
    {
      // stage K tile (natural layout)
      int r = tid >> 3, c8 = tid & 7;
      const bf16x8* src = (const bf16x8*)&kd[(hrow + kt * 32 + r) * DH + c8 * 16];
      bf16x8* dst = (bf16x8*)&Ks[r][c8 * 16];
      dst[0] = src[0]; dst[1] = src[1];
      // stage V tile from pre-transposed vdt
      int d = tid >> 1, h = tid & 1;
      const bf16x8* vs = (const bf16x8*)&vdt[((long)head * DH + d) * SLEN + kt * 32 + h * 16];
      bf16x8* vd = (bf16x8*)&Vt[d][h * 16];
      vd[0] = vs[0]; vd[1] = vs[1];
    }
    __syncthreads();

    // S = Q K^T (C-layout: col=key=L, row=q=quad*4+r)
    f32x4 sf[2][2];
    #pragma unroll
    for (int g = 0; g < 2; ++g)
      #pragma unroll
      for (int kk = 0; kk < 2; ++kk) sf[g][kk] = (f32x4){0.f,0.f,0.f,0.f};
    #pragma unroll
    for (int kk = 0; kk < 2; ++kk) {
      #pragma unroll
      for (int c = 0; c < 4; ++c) {
        bf16x8 kb = *(const bf16x8*)&Ks[kk * 16 + L][c * 32 + quad * 8];
        sf[0][kk] = mfma16(aq[0][c], kb, sf[0][kk]);
        sf[1][kk] = mfma16(aq[1][c], kb, sf[1][kk]);
      }
    }

    // p = exp(s - M), accumulate row-sum partials, write P to LDS
    #pragma unroll
    for (int g = 0; g < 2; ++g) {
      #pragma unroll
      for (int r = 0; r < 4; ++r) {
        float p0 = __expf(sf[g][0][r] - Mrow[g][r]);
        float p1 = __expf(sf[g][1][r] - Mrow[g][r]);
        lrow[g][r] += p0 + p1;
        Ps[wave][g * 16 + quad * 4 + r][L]      = p0;
        Ps[wave][g * 16 + quad * 4 + r][16 + L] = p1;
      }
    }
    asm volatile("s_waitcnt lgkmcnt(0)" ::: "memory");

    // read P in A-layout, PV MFMAs
    bf16x8 pa[2];
    #pragma unroll
    for (int g = 0; g < 2; ++g) {
      f32x4 plo = *(const f32x4*)&Ps[wave][g * 16 + L][quad * 8];
      f32x4 phi = *(const f32x4*)&Ps[wave][g * 16 + L][quad * 8 + 4];
      #pragma unroll
      for (int j = 0; j < 4; ++j) { pa[g][j] = (__bf16)plo[j]; pa[g][4 + j] = (__bf16)phi[j]; }
    }
    #pragma unroll
    for (int c = 0; c < 8; ++c) {
      bf16x8 vb = *(const bf16x8*)&Vt[c * 16 + L][quad * 8];
      o[0][c] = mfma16(pa[0], vb, o[0][c]);
      o[1][c] = mfma16(pa[1], vb, o[1][c]);
    }
  }

  // finish row sums (reduce over the 16 key-lanes) and normalize
  #pragma unroll
  for (int g = 0; g < 2; ++g)
    #pragma unroll
    for (int r = 0; r < 4; ++r) {
      float s = lrow[g][r];
      s += __shfl_xor(s, 1, 64); s += __shfl_xor(s, 2, 64);
      s += __shfl_xor(s, 4, 64); s += __shfl_xor(s, 8, 64);
      lrow[g][r] = 1.0f / s;
    }
  #pragma unroll
  for (int g = 0; g < 2; ++g)
    #pragma unroll
    for (int c = 0; c < 8; ++c) {
      f32x4 ov = o[g][c];
      #pragma unroll
      for (int r = 0; r < 4; ++r)
        orot[(hrow + qbase + g * 16 + quad * 4 + r) * DH + c * 16 + L] = ov[r] * lrow[g][r];
    }
}

// ---------------------------------------------------------------------------
extern "C" void kernel_launch(void* const* d_in, const int* in_sizes, int n_in,
                              void* d_out, int out_size, void* d_ws, size_t ws_size,
                              hipStream_t stream)
{
  const float* q   = (const float*)d_in[0];
  const float* k   = (const float*)d_in[1];
  const float* v   = (const float*)d_in[2];
  const float* R   = (const float*)d_in[3];
  const float* qjl = (const float*)d_in[4];

  char* ws = (char*)d_ws;
  float* kpart = (float*)ws;                    // [1024]
  float* vpart = kpart + 1024;                  // [1024]
  float* kvmax = vpart + 1024;                  // [2]
  float* qn    = (float*)(ws + 16384);          // [65536] row norms of scaled qR
  char* base   = ws + 16384 + 262144;
  __bf16* qb  = (__bf16*)base;                                    // 16 MiB
  float*  kr  = (float*)(base + (1u << 24));                      // 32 MiB (-> orot)
  float*  vr  = (float*)(base + (1u << 24) + (1u << 25));         // 32 MiB (-> kd)
  __bf16* vdt = (__bf16*)(base + (1u << 24) + 2u * (1u << 25));   // 16 MiB
  __bf16* kd  = (__bf16*)vr;   // reuse vr region after vr consumed
  float* orot = kr;            // reuse kr region after kd built

  dim3 b256(256);
  rotate_kernel<0><<<1024, b256, 0, stream>>>(q, R, (void*)qb, nullptr, qn);
  rotate_kernel<1><<<1024, b256, 0, stream>>>(k, R, (void*)kr, kpart, nullptr);
  rotate_kernel<2><<<1024, b256, 0, stream>>>(v, R, (void*)vr, vpart, nullptr);
  reduce_max_kernel<<<1, b256, 0, stream>>>(kpart, kvmax);
  quantize_vt_kernel<<<2048, b256, 0, stream>>>(vr, &kvmax[1], qjl, vdt);
  quantize_k_kernel<<<8192, b256, 0, stream>>>(kr, &kvmax[0], qjl, kd);
  attn_kernel<<<512, b256, 0, stream>>>(qb, kd, vdt, qn, kvmax, qjl, orot);
  rotate_kernel<3><<<1024, b256, 0, stream>>>(orot, R, d_out, nullptr, nullptr);
}

// Round 2
// 331.339 us; speedup vs baseline: 1.2038x; 1.2038x over previous
//
#include <hip/hip_runtime.h>

// ---------------------------------------------------------------------------
// TurboQuantAttention — round 2.
// All rotations via MFMA (f16 hi/lo 3-term for k/v to preserve quantization
// bins; single-pass f16 for q/out). Attention uses the S^T trick: 32x32x16
// QK^T output C-layout IS the 32x32x8 PV A-layout, so P never leaves regs.
// K tile XOR-swizzled in LDS + global_load_lds DMA; V tile padded u64 rows.
// ---------------------------------------------------------------------------

typedef float    f32x4  __attribute__((ext_vector_type(4)));
typedef float    f32x16 __attribute__((ext_vector_type(16)));
typedef __bf16   bf16x8 __attribute__((ext_vector_type(8)));
typedef __bf16   bf16x4 __attribute__((ext_vector_type(4)));
typedef _Float16 f16x8  __attribute__((ext_vector_type(8)));
typedef short    s16x4  __attribute__((ext_vector_type(4)));
typedef unsigned long long u64;

#define SLEN 2048
#define DH   128

static __device__ __forceinline__ f32x16 zero16() {
  f32x16 z;
#pragma unroll
  for (int i = 0; i < 16; ++i) z[i] = 0.f;
  return z;
}

static __device__ __forceinline__ f32x16 mfma_bf16_32x32x16(bf16x8 a, bf16x8 b, f32x16 c) {
  return __builtin_amdgcn_mfma_f32_32x32x16_bf16(a, b, c, 0, 0, 0);
}
static __device__ __forceinline__ f32x16 mfma_f16_32x32x16(f16x8 a, f16x8 b, f32x16 c) {
  return __builtin_amdgcn_mfma_f32_32x32x16_f16(a, b, c, 0, 0, 0);
}
static __device__ __forceinline__ f32x16 mfma_bf16_32x32x8(s16x4 a, s16x4 b, f32x16 c) {
  return __builtin_amdgcn_mfma_f32_32x32x8bf16_1k(a, b, c, 0, 0, 0);
}

// async global->LDS, 16B per lane; lds base is wave-uniform, lane i lands at +i*16
static __device__ __forceinline__ void lds_dma16(const void* g, void* l) {
  __builtin_amdgcn_global_load_lds(
      (const __attribute__((address_space(1))) void*)(unsigned long long)g,
      (__attribute__((address_space(3))) void*)(unsigned int)(unsigned long long)l,
      16, 0, 0);
}

// quantize->dequantize one element, op-order identical to reference (fp32)
static __device__ __forceinline__ float qdq(float xr, float xmax, float qs) {
  float xs = xr / xmax * 3.5f;
  float xq = rintf(xs * 4.0f) * 0.25f;
  xq = fminf(3.5f, fmaxf(-3.5f, xq));
  float res = xs - xq;
  float sg = (res > 0.0f) ? 1.0f : ((res < 0.0f) ? -1.0f : 0.0f);
  float xc = xq + sg * qs * xmax;
  return xc / 3.5f * xmax;
}

static __device__ __forceinline__ unsigned short bfbits(float f) {
  __bf16 b = (__bf16)f;
  return __builtin_bit_cast(unsigned short, b);
}

// ---------------------------------------------------------------------------
// prep_R: split R (fp32 128x128) into f16 hi/lo, row-major and transposed.
// ---------------------------------------------------------------------------
__global__ __launch_bounds__(256) void prep_R(
    const float* __restrict__ R, _Float16* __restrict__ Bhi,
    _Float16* __restrict__ Blo, _Float16* __restrict__ BhiT,
    _Float16* __restrict__ BloT)
{
  int i = blockIdx.x * 256 + threadIdx.x;   // 0..16383
  int kk = i >> 7, n = i & 127;
  float r = R[i];
  _Float16 h = (_Float16)r;
  _Float16 l = (_Float16)(r - (float)h);
  Bhi[i] = h; Blo[i] = l;
  BhiT[n * 128 + kk] = h; BloT[n * 128 + kk] = l;
}

// ---------------------------------------------------------------------------
// rot_mfma: C = X(65536x128) @ B^T  where B[n][k] is the staged matrix.
//   For X@R pass B = R^T (BhiT/BloT); for X@R^T pass B = R (Bhi/Blo).
// NT=3: f16 hi/lo 3-term (fp32-grade precision); NT=1: f16 single pass.
// MODE 0: fp32 out + per-wave absmax -> part[blockIdx*4+wave]
// MODE 1: bf16 out scaled by 1/sqrt(128)   (q path)
// MODE 2: fp32 out                          (final unrotate)
// Block: 256 thr = 4 waves; 128 rows/block; wave = 32 rows x 128 cols.
// ---------------------------------------------------------------------------
template<int NT, int MODE>
__global__ __launch_bounds__(256) void rot_mfma(
    const float* __restrict__ X, const _Float16* __restrict__ Gh,
    const _Float16* __restrict__ Gl, void* __restrict__ OUTv,
    float* __restrict__ part)
{
  __shared__ _Float16 BH[128 * 128];
  __shared__ _Float16 BL[(NT == 3) ? 128 * 128 : 8];

  const int tid = threadIdx.x, wave = tid >> 6, lane = tid & 63;
  const int r31 = lane & 31, hi = lane >> 5;
  const long r0 = (long)blockIdx.x * 128;

  // stage B via DMA, XOR-swizzled at 16B-chunk granularity
#pragma unroll
  for (int u = 0; u < 8; ++u) {
    int c = (wave * 8 + u) * 64 + lane;
    int n = c >> 4, p = c & 15, ch = p ^ (n & 7);
    lds_dma16(Gh + n * 128 + ch * 8, BH + (wave * 8 + u) * 512);
    if constexpr (NT == 3)
      lds_dma16(Gl + n * 128 + ch * 8, BL + (wave * 8 + u) * 512);
  }

  // A: load X rows direct from global, split f16 hi/lo in regs
  const long rowg = r0 + wave * 32 + r31;
  f16x8 ah[8], al[8];
#pragma unroll
  for (int t = 0; t < 8; ++t) {
    f32x4 x0 = *(const f32x4*)&X[rowg * 128 + t * 16 + hi * 8];
    f32x4 x1 = *(const f32x4*)&X[rowg * 128 + t * 16 + hi * 8 + 4];
#pragma unroll
    for (int j = 0; j < 4; ++j) {
      _Float16 h0 = (_Float16)x0[j]; ah[t][j] = h0;
      _Float16 h1 = (_Float16)x1[j]; ah[t][4 + j] = h1;
      if constexpr (NT == 3) {
        al[t][j]     = (_Float16)(x0[j] - (float)h0);
        al[t][4 + j] = (_Float16)(x1[j] - (float)h1);
      }
    }
  }
  __syncthreads();

  f32x16 acc[4];
#pragma unroll
  for (int ct = 0; ct < 4; ++ct) acc[ct] = zero16();

#pragma unroll
  for (int ct = 0; ct < 4; ++ct) {
#pragma unroll
    for (int t = 0; t < 8; ++t) {
      int idx = (ct * 32 + r31) * 128 + (((2 * t + hi) ^ (r31 & 7)) * 8);
      f16x8 bh = *(const f16x8*)&BH[idx];
      acc[ct] = mfma_f16_32x32x16(ah[t], bh, acc[ct]);
      if constexpr (NT == 3) {
        f16x8 bl = *(const f16x8*)&BL[idx];
        acc[ct] = mfma_f16_32x32x16(ah[t], bl, acc[ct]);
        acc[ct] = mfma_f16_32x32x16(al[t], bh, acc[ct]);
      }
    }
  }

  if constexpr (MODE == 0) {
    float* OUT = (float*)OUTv;
    float am = 0.f;
#pragma unroll
    for (int ct = 0; ct < 4; ++ct)
#pragma unroll
      for (int r = 0; r < 16; ++r) {
        long grow = r0 + wave * 32 + (r & 3) + 8 * (r >> 2) + 4 * hi;
        float v = acc[ct][r];
        OUT[grow * 128 + ct * 32 + r31] = v;
        am = fmaxf(am, fabsf(v));
      }
#pragma unroll
    for (int m = 1; m <= 32; m <<= 1) am = fmaxf(am, __shfl_xor(am, m, 64));
    if (lane == 0) part[blockIdx.x * 4 + wave] = am;
  } else if constexpr (MODE == 1) {
    __bf16* OUT = (__bf16*)OUTv;
    const float sc = 0.08838834764831843f;   // 1/sqrt(128)
#pragma unroll
    for (int ct = 0; ct < 4; ++ct)
#pragma unroll
      for (int r = 0; r < 16; ++r) {
        long grow = r0 + wave * 32 + (r & 3) + 8 * (r >> 2) + 4 * hi;
        OUT[grow * 128 + ct * 32 + r31] = (__bf16)(acc[ct][r] * sc);
      }
  } else {
    float* OUT = (float*)OUTv;
#pragma unroll
    for (int ct = 0; ct < 4; ++ct)
#pragma unroll
      for (int r = 0; r < 16; ++r) {
        long grow = r0 + wave * 32 + (r & 3) + 8 * (r >> 2) + 4 * hi;
        OUT[grow * 128 + ct * 32 + r31] = acc[ct][r];
      }
  }
}

// row norms of scaled bf16 q (consistent with MFMA inputs)
__global__ __launch_bounds__(256) void qn_kernel(
    const __bf16* __restrict__ qb, float* __restrict__ qn)
{
  int t = blockIdx.x * 256 + threadIdx.x;
  int row = t >> 1, h = t & 1;
  const bf16x8* p = (const bf16x8*)&qb[(long)row * 128 + h * 64];
  float s = 0.f;
#pragma unroll
  for (int u = 0; u < 8; ++u) {
    bf16x8 x = p[u];
#pragma unroll
    for (int j = 0; j < 8; ++j) { float f = (float)x[j]; s += f * f; }
  }
  s += __shfl_xor(s, 1, 64);
  if (h == 0) qn[row] = sqrtf(s);
}

// reduce 2048 k-partials and 2048 v-partials to kvmax[0], kvmax[1]
__global__ __launch_bounds__(256) void reduce_max_kernel(
    const float* __restrict__ part, float* __restrict__ outmax)
{
  __shared__ float s4[4];
  const int tid = threadIdx.x;
  for (int which = 0; which < 2; ++which) {
    const float* p = part + which * 2048;
    float m = 0.f;
    for (int i = tid; i < 2048; i += 256) m = fmaxf(m, p[i]);
#pragma unroll
    for (int msk = 1; msk <= 32; msk <<= 1) m = fmaxf(m, __shfl_xor(m, msk, 64));
    if ((tid & 63) == 0) s4[tid >> 6] = m;
    __syncthreads();
    if (tid == 0) outmax[which] = fmaxf(fmaxf(s4[0], s4[1]), fmaxf(s4[2], s4[3]));
    __syncthreads();
  }
}

// elementwise quantize+dequant k -> bf16 natural layout
__global__ __launch_bounds__(256) void quantize_k_kernel(
    const float* __restrict__ xr, const float* __restrict__ gmax,
    const float* __restrict__ qjl, __bf16* __restrict__ out)
{
  const float xmax = gmax[0] + 1e-8f;
  const float qs = qjl[0];
  long i = ((long)blockIdx.x * 256 + threadIdx.x) * 4;
  f32x4 x = *(const f32x4*)&xr[i];
  bf16x4 ov;
#pragma unroll
  for (int j = 0; j < 4; ++j) ov[j] = (__bf16)qdq(x[j], xmax, qs);
  *(bf16x4*)&out[i] = ov;
}

// quantize+dequant v -> bf16 TRANSPOSED per head: vdt[bh][d][s]
__global__ __launch_bounds__(256) void quantize_vt_kernel(
    const float* __restrict__ vr, const float* __restrict__ gmax,
    const float* __restrict__ qjl, __bf16* __restrict__ vdt)
{
  __shared__ unsigned int Ts32[128][18];
  const int tid = threadIdx.x;
  const int bh = blockIdx.x >> 6;
  const int s0 = (blockIdx.x & 63) * 32;
  const float xmax = gmax[0] + 1e-8f;
  const float qs = qjl[0];

  const int sp  = tid & 15;
  const int dch = tid >> 4;
  const long rb = (long)bh * SLEN + s0;
  const float* p0 = &vr[(rb + sp * 2    ) * 128 + dch * 8];
  const float* p1 = &vr[(rb + sp * 2 + 1) * 128 + dch * 8];
#pragma unroll
  for (int j = 0; j < 8; ++j) {
    unsigned a = bfbits(qdq(p0[j], xmax, qs));
    unsigned b = bfbits(qdq(p1[j], xmax, qs));
    Ts32[dch * 8 + j][sp] = a | (b << 16);
  }
  __syncthreads();
  const int d = tid >> 1, h = tid & 1;
  const u64* srcq = (const u64*)((const unsigned short*)&Ts32[d][0] + h * 16);
  u64* dstq = (u64*)&vdt[((long)bh * DH + d) * SLEN + s0 + h * 16];
  dstq[0] = srcq[0]; dstq[1] = srcq[1]; dstq[2] = srcq[2]; dstq[3] = srcq[3];
}

// ---------------------------------------------------------------------------
// attn2: flash attention in rotated space.
// S^T = K Q^T via 32x32x16 bf16 MFMA (A=K, B=Q). The C-layout of S^T
// (col=lane&31=q, row=(reg&3)+8(reg>>2)+4hi=key) is exactly the A-layout of
// 32x32x8 PV MFMA (m=q=lane&31, k=key, subtile s <- regs 4s..4s+3), so P
// stays in registers. Static per-row softmax bound (no online max).
// ---------------------------------------------------------------------------
__global__ __launch_bounds__(256) void attn2(
    const __bf16* __restrict__ qb, const __bf16* __restrict__ kd,
    const __bf16* __restrict__ vdt, const float* __restrict__ qn,
    const float* __restrict__ kvmax, const float* __restrict__ qjl,
    float* __restrict__ orot)
{
  __shared__ __bf16 Ks[32 * 128];   // XOR-swizzled 16B chunks
  __shared__ u64   VtQ[128 * 9];    // V^T tile, 72B row stride (pad -> 2-way free)
  __shared__ float Ls[4][32];

  const int tid = threadIdx.x, wave = tid >> 6, lane = tid & 63;
  const int r31 = lane & 31, hi = lane >> 5;
  const int head = blockIdx.x & 31, qt = blockIdx.x >> 5;
  const long hrow = (long)head * SLEN;
  const int qrow0 = qt * 128 + wave * 32;

  const float xmax = kvmax[0] + 1e-8f;
  const float Bk = 11.313708499f * ((3.5f + qjl[0] * xmax) * xmax / 3.5f) * 1.02f * 0.5f;

  // Q fragments, B-layout of 32x32x16: B[n=lane&31][k=hi*8+j], scale pre-folded
  bf16x8 qf[8];
#pragma unroll
  for (int t = 0; t < 8; ++t)
    qf[t] = *(const bf16x8*)&qb[(hrow + qrow0 + r31) * DH + t * 16 + hi * 8];

  const float Mq = qn[hrow + qrow0 + r31] * Bk;
  float lsum = 0.f;

  // Ks LDS read byte-offsets (kt-invariant): chunk (2t+hi) XOR (row&7)
  int koff[8];
#pragma unroll
  for (int t = 0; t < 8; ++t)
    koff[t] = r31 * 256 + (((2 * t + hi) ^ (r31 & 7)) << 4);

  // DMA source element-offsets (swizzle-compensated)
  long gidx[2]; int ldsc[2];
#pragma unroll
  for (int u = 0; u < 2; ++u) {
    int c = (wave * 2 + u) * 64 + lane;
    int row = c >> 4, ch = (c & 15) ^ (row & 7);
    gidx[u] = (hrow + row) * DH + ch * 8;
    ldsc[u] = (wave * 2 + u) * 512;
  }

  // V staging: thread covers row d, keys h*16..h*16+15
  const int vd = tid >> 1, vh = tid & 1;
  const __bf16* vsrc = &vdt[((long)head * DH + vd) * SLEN + vh * 16];

  f32x16 acc[4];
#pragma unroll
  for (int dt = 0; dt < 4; ++dt) acc[dt] = zero16();

  for (int kt = 0; kt < SLEN / 32; ++kt) {
    __syncthreads();
    lds_dma16(kd + gidx[0] + (long)kt * 32 * DH, &Ks[ldsc[0]]);
    lds_dma16(kd + gidx[1] + (long)kt * 32 * DH, &Ks[ldsc[1]]);
    {
      const bf16x8* vs = (const bf16x8*)(vsrc + kt * 32);
      union { bf16x8 v; u64 q[2]; } ua, ub;
      ua.v = vs[0]; ub.v = vs[1];
      VtQ[vd * 9 + vh * 4 + 0] = ua.q[0];
      VtQ[vd * 9 + vh * 4 + 1] = ua.q[1];
      VtQ[vd * 9 + vh * 4 + 2] = ub.q[0];
      VtQ[vd * 9 + vh * 4 + 3] = ub.q[1];
    }
    __syncthreads();

    // S^T = K Q^T
    f32x16 s = zero16();
#pragma unroll
    for (int t = 0; t < 8; ++t) {
      bf16x8 ka = *(const bf16x8*)((const char*)Ks + koff[t]);
      s = mfma_bf16_32x32x16(ka, qf[t], s);
    }

    // softmax numerator, P in registers
    float p[16];
#pragma unroll
    for (int r = 0; r < 16; ++r) { p[r] = __expf(s[r] - Mq); lsum += p[r]; }

    // PV: O[q][d] += P V, 32x32x8, A = P (from regs), B = V^T tile
#pragma unroll
    for (int st = 0; st < 4; ++st) {
      bf16x4 pb;
#pragma unroll
      for (int j = 0; j < 4; ++j) pb[j] = (__bf16)p[st * 4 + j];
      s16x4 pa = __builtin_bit_cast(s16x4, pb);
#pragma unroll
      for (int dt = 0; dt < 4; ++dt) {
        s16x4 vb = __builtin_bit_cast(s16x4, VtQ[(dt * 32 + r31) * 9 + st * 2 + hi]);
        acc[dt] = mfma_bf16_32x32x8(pa, vb, acc[dt]);
      }
    }
  }

  lsum += __shfl_xor(lsum, 32, 64);
  if (hi == 0) Ls[wave][r31] = 1.0f / lsum;
  __syncthreads();

#pragma unroll
  for (int dt = 0; dt < 4; ++dt)
#pragma unroll
    for (int r = 0; r < 16; ++r) {
      int qr = (r & 3) + 8 * (r >> 2) + 4 * hi;
      orot[(hrow + qrow0 + qr) * DH + dt * 32 + r31] = acc[dt][r] * Ls[wave][qr];
    }
}

// ---------------------------------------------------------------------------
extern "C" void kernel_launch(void* const* d_in, const int* in_sizes, int n_in,
                              void* d_out, int out_size, void* d_ws, size_t ws_size,
                              hipStream_t stream)
{
  const float* q   = (const float*)d_in[0];
  const float* k   = (const float*)d_in[1];
  const float* v   = (const float*)d_in[2];
  const float* R   = (const float*)d_in[3];
  const float* qjl = (const float*)d_in[4];

  char* ws = (char*)d_ws;
  float* kpart = (float*)ws;                      // [2048]
  float* vpart = (float*)(ws + 8192);             // [2048] (must be kpart+2048)
  float* kvmax = (float*)(ws + 16384);            // [2]
  _Float16* Bhi  = (_Float16*)(ws + 32768);       // R row-major f16 hi (32KB)
  _Float16* Blo  = (_Float16*)(ws + 65536);
  _Float16* BhiT = (_Float16*)(ws + 98304);       // R^T f16 hi
  _Float16* BloT = (_Float16*)(ws + 131072);
  float* qn = (float*)(ws + 163840);              // [65536] (256KB)
  char* base = ws + 425984;
  __bf16* qb  = (__bf16*)base;                                  // 16 MiB
  float*  kr  = (float*)(base + (16u << 20));                   // 32 MiB
  float*  vr  = (float*)(base + (48u << 20));                   // 32 MiB
  __bf16* vdt = (__bf16*)(base + (80u << 20));                  // 16 MiB
  __bf16* kd  = (__bf16*)vr;    // reuse vr after quantize_vt consumed it
  float* orot = kr;             // reuse kr after quantize_k consumed it

  dim3 b256(256);
  prep_R<<<64, b256, 0, stream>>>(R, Bhi, Blo, BhiT, BloT);
  rot_mfma<3, 0><<<512, b256, 0, stream>>>(k, BhiT, BloT, (void*)kr, kpart);
  rot_mfma<3, 0><<<512, b256, 0, stream>>>(v, BhiT, BloT, (void*)vr, vpart);
  rot_mfma<1, 1><<<512, b256, 0, stream>>>(q, BhiT, BloT, (void*)qb, nullptr);
  qn_kernel<<<512, b256, 0, stream>>>(qb, qn);
  reduce_max_kernel<<<1, b256, 0, stream>>>(kpart, kvmax);
  quantize_vt_kernel<<<2048, b256, 0, stream>>>(vr, &kvmax[1], qjl, vdt);
  quantize_k_kernel<<<8192, b256, 0, stream>>>(kr, &kvmax[0], qjl, kd);
  attn2<<<512, b256, 0, stream>>>(qb, kd, vdt, qn, kvmax, qjl, orot);
  rot_mfma<1, 2><<<512, b256, 0, stream>>>(orot, Bhi, Blo, d_out, nullptr);
}